// Round 1
// baseline (1124.358 us; speedup 1.0000x reference)
//
#include <hip/hip_runtime.h>
#include <math.h>

#define T_STEPS 1024
#define B_SIZE  512
#define D_IN    225
#define LOG2E   1.4426950408889634f

__device__ __forceinline__ float fexp2(float x) {
#if __has_builtin(__builtin_amdgcn_exp2f)
  return __builtin_amdgcn_exp2f(x);
#else
  return exp2f(x);
#endif
}
__device__ __forceinline__ float frcp(float x) {
#if __has_builtin(__builtin_amdgcn_rcpf)
  return __builtin_amdgcn_rcpf(x);
#else
  return 1.0f / x;
#endif
}

// ---------------- Kernel 1: xg = x @ Wih0^T + bih0 + bhh0  -> [B*T, 20] ----
// Thread-per-row; W/bias accesses are uniform -> SGPR loads; x is streamed
// scalar but wave-synchronous in k so the live set is 64 lines -> L1 reuse.
__global__ __launch_bounds__(256)
void xg_gemm(const float* __restrict__ x, const float* __restrict__ Wih,
             const float* __restrict__ bih, const float* __restrict__ bhh,
             float* __restrict__ xg)
{
  int row = blockIdx.x * 256 + threadIdx.x;       // 0 .. B*T-1 exactly
  const float* xr = x + (size_t)row * D_IN;
  float acc[20];
#pragma unroll
  for (int gi = 0; gi < 20; ++gi) acc[gi] = bih[gi] + bhh[gi];
#pragma unroll 5
  for (int k = 0; k < D_IN; ++k) {
    float xv = xr[k];
#pragma unroll
    for (int gi = 0; gi < 20; ++gi)
      acc[gi] = fmaf(xv, Wih[gi * D_IN + k], acc[gi]);
  }
  float4* o = (float4*)(xg + (size_t)row * 20);   // row*80B is 16B aligned
#pragma unroll
  for (int q = 0; q < 5; ++q)
    o[q] = make_float4(acc[4*q], acc[4*q+1], acc[4*q+2], acc[4*q+3]);
}

// ---------------- Kernel 2: fused 4-layer LSTM + FCs, layer-pipelined ------
__device__ __forceinline__ void bcast5(float v, float (&dst)[5]) {
#pragma unroll
  for (int j = 0; j < 5; ++j) dst[j] = __shfl(v, j, 32);
}

__device__ __forceinline__ float activ(float pre, float premul, float postA, float postB) {
  float e = fexp2(pre * premul);
  float s = frcp(1.0f + e);
  return fmaf(postA, s, postB);
}

template <bool HAS_IN>
__device__ __forceinline__ void lstm_stage(const float (&wih)[5], const float (&whh)[5],
                                           float bias_or_xg, const float (&in)[5],
                                           float (&h)[5], float& c,
                                           float premul, float postA, float postB)
{
  float pre = bias_or_xg;
  if (HAS_IN) {
#pragma unroll
    for (int k = 0; k < 5; ++k) pre = fmaf(wih[k], in[k], pre);
  }
#pragma unroll
  for (int k = 0; k < 5; ++k) pre = fmaf(whh[k], h[k], pre);
  // lane g<15: sigmoid; 10<=g<15 tanh -- encoded in per-lane consts
  float a  = activ(pre, premul, postA, postB);
  // unit lanes (g<5): i = own a, f from g+5, g~ from g+10, o from g+15
  float f  = __shfl_down(a, 5, 32);
  float gg = __shfl_down(a, 10, 32);
  float o  = __shfl_down(a, 15, 32);
  float cn = fmaf(f, c, a * gg);
  c = cn;
  float e2 = fexp2(cn * (-2.0f * LOG2E));
  float th = fmaf(2.0f, frcp(1.0f + e2), -1.0f);
  float hv = o * th;
  bcast5(hv, h);
}

__device__ __forceinline__ float fc_eval(const float (&w)[5], float b, const float (&in)[5]) {
  float v = b;
#pragma unroll
  for (int k = 0; k < 5; ++k) v = fmaf(w[k], in[k], v);
  return v;
}

// One pipeline tick. Stage t-offsets: FC2 t=k-5, L3 t=k-4, L2 t=k-3,
// FC1 t=k-2, L1 t=k-1, L0 t=k. Reverse dataflow order -> no copies needed.
#define TICK(GUARDED)                                                          \
  {                                                                            \
    if (!(GUARDED) || (k >= 5)) {                                              \
      float v  = fc_eval(w2, fb2, h3);                                         \
      float sg = frcp(1.0f + fexp2(v * (-LOG2E)));                             \
      if (g < 5) out[(rowbase + (k - 5)) * 5 + g] = sg;                        \
    }                                                                          \
    if (!(GUARDED) || (k >= 4 && k < T_STEPS + 4))                             \
      lstm_stage<true>(wih3, whh3, b3, h2, h3, c3, premul, postA, postB);      \
    if (!(GUARDED) || (k >= 3 && k < T_STEPS + 3))                             \
      lstm_stage<true>(wih2, whh2, b2, y, h2, c2, premul, postA, postB);       \
    if (!(GUARDED) || (k >= 2 && k < T_STEPS + 2)) {                           \
      float v = fc_eval(w1, fb1, h1);                                          \
      v = fmaxf(v, 0.0f);                                                      \
      bcast5(v, y);                                                            \
    }                                                                          \
    if (!(GUARDED) || (k >= 1 && k < T_STEPS + 1))                             \
      lstm_stage<true>(wih1, whh1, b1, h0, h1, c1, premul, postA, postB);      \
    if (!(GUARDED) || (k < T_STEPS))                                           \
      lstm_stage<false>(whh0, whh0, xq0, h0, h0, c0, premul, postA, postB);    \
    xq0 = xq1; xq1 = xq2;                                                      \
    { int tn = k + 3; if (tn > T_STEPS - 1) tn = T_STEPS - 1;                  \
      xq2 = act20 ? xgp[(size_t)tn * 20] : 0.0f; }                             \
  }

__global__ __launch_bounds__(64)
void lstm_rec(const float* __restrict__ xg, float* __restrict__ out,
              const float* __restrict__ l1_Whh0,
              const float* __restrict__ l1_Wih1, const float* __restrict__ l1_Whh1,
              const float* __restrict__ l1_bih1, const float* __restrict__ l1_bhh1,
              const float* __restrict__ fc1_W,  const float* __restrict__ fc1_b,
              const float* __restrict__ l2_Wih0, const float* __restrict__ l2_Whh0,
              const float* __restrict__ l2_bih0, const float* __restrict__ l2_bhh0,
              const float* __restrict__ l2_Wih1, const float* __restrict__ l2_Whh1,
              const float* __restrict__ l2_bih1, const float* __restrict__ l2_bhh1,
              const float* __restrict__ fc2_W,  const float* __restrict__ fc2_b)
{
  const int lane = threadIdx.x;       // 0..63, one wave per block
  const int g    = lane & 31;         // gate index within batch element
  const int half = lane >> 5;
  const int b    = blockIdx.x * 2 + half;
  const bool act20 = (g < 20);
  const int gs = act20 ? g : 0;       // clamp for safe (garbage) loads
  const int gf = (g < 5) ? g : 0;

  float whh0[5], wih1[5], whh1[5], wih2[5], whh2[5], wih3[5], whh3[5];
  float w1[5], w2[5];
#pragma unroll
  for (int k = 0; k < 5; ++k) {
    whh0[k] = l1_Whh0[gs * 5 + k];
    wih1[k] = l1_Wih1[gs * 5 + k];
    whh1[k] = l1_Whh1[gs * 5 + k];
    wih2[k] = l2_Wih0[gs * 5 + k];
    whh2[k] = l2_Whh0[gs * 5 + k];
    wih3[k] = l2_Wih1[gs * 5 + k];
    whh3[k] = l2_Whh1[gs * 5 + k];
    w1[k]   = fc1_W[gf * 5 + k];
    w2[k]   = fc2_W[gf * 5 + k];
  }
  float b1  = l1_bih1[gs] + l1_bhh1[gs];
  float b2  = l2_bih0[gs] + l2_bhh0[gs];
  float b3  = l2_bih1[gs] + l2_bhh1[gs];
  float fb1 = fc1_b[gf];
  float fb2 = fc2_b[gf];

  // torch gate order i,f,g,o -> lanes 10..14 are tanh, rest sigmoid
  const bool  is_t   = (g >= 10 && g < 15);
  const float premul = is_t ? (-2.0f * LOG2E) : (-LOG2E);
  const float postA  = is_t ? 2.0f : 1.0f;
  const float postB  = is_t ? -1.0f : 0.0f;

  float h0[5] = {0,0,0,0,0}, h1[5] = {0,0,0,0,0};
  float h2[5] = {0,0,0,0,0}, h3[5] = {0,0,0,0,0};
  float y[5]  = {0,0,0,0,0};
  float c0 = 0.f, c1 = 0.f, c2 = 0.f, c3 = 0.f;

  const size_t rowbase = (size_t)b * T_STEPS;
  const float* xgp = xg + rowbase * 20 + g;   // advance 20 floats per t

  // prefetch queue (depth 3 ~ 900 cycles of cover)
  float xq0 = act20 ? xgp[0]  : 0.0f;
  float xq1 = act20 ? xgp[20] : 0.0f;
  float xq2 = act20 ? xgp[40] : 0.0f;

  int k = 0;
  for (; k < 5; ++k)             TICK(true)    // pipeline fill
  for (; k < T_STEPS; ++k)       TICK(false)   // steady state, branchless
  for (; k < T_STEPS + 5; ++k)   TICK(true)    // drain
}

// ---------------------------------------------------------------------------
extern "C" void kernel_launch(void* const* d_in, const int* in_sizes, int n_in,
                              void* d_out, int out_size, void* d_ws, size_t ws_size,
                              hipStream_t stream)
{
  const float* x        = (const float*)d_in[0];
  const float* l1_Wih0  = (const float*)d_in[1];
  const float* l1_Whh0  = (const float*)d_in[2];
  const float* l1_bih0  = (const float*)d_in[3];
  const float* l1_bhh0  = (const float*)d_in[4];
  const float* l1_Wih1  = (const float*)d_in[5];
  const float* l1_Whh1  = (const float*)d_in[6];
  const float* l1_bih1  = (const float*)d_in[7];
  const float* l1_bhh1  = (const float*)d_in[8];
  const float* fc1_W    = (const float*)d_in[9];
  const float* fc1_b    = (const float*)d_in[10];
  const float* l2_Wih0  = (const float*)d_in[11];
  const float* l2_Whh0  = (const float*)d_in[12];
  const float* l2_bih0  = (const float*)d_in[13];
  const float* l2_bhh0  = (const float*)d_in[14];
  const float* l2_Wih1  = (const float*)d_in[15];
  const float* l2_Whh1  = (const float*)d_in[16];
  const float* l2_bih1  = (const float*)d_in[17];
  const float* l2_bhh1  = (const float*)d_in[18];
  const float* fc2_W    = (const float*)d_in[19];
  const float* fc2_b    = (const float*)d_in[20];

  float* xg  = (float*)d_ws;            // needs B*T*20*4 = 41,943,040 bytes
  float* out = (float*)d_out;

  xg_gemm<<<dim3((B_SIZE * T_STEPS) / 256), dim3(256), 0, stream>>>(
      x, l1_Wih0, l1_bih0, l1_bhh0, xg);

  lstm_rec<<<dim3(B_SIZE / 2), dim3(64), 0, stream>>>(
      xg, out, l1_Whh0, l1_Wih1, l1_Whh1, l1_bih1, l1_bhh1,
      fc1_W, fc1_b, l2_Wih0, l2_Whh0, l2_bih0, l2_bhh0,
      l2_Wih1, l2_Whh1, l2_bih1, l2_bhh1, fc2_W, fc2_b);
}

// Round 2
// 831.421 us; speedup vs baseline: 1.3523x; 1.3523x over previous
//
#include <hip/hip_runtime.h>
#include <math.h>

#define T_STEPS 1024
#define B_SIZE  512
#define D_IN    225
#define LOG2E   1.4426950408889634f

__device__ __forceinline__ float fexp2(float x) {
#if __has_builtin(__builtin_amdgcn_exp2f)
  return __builtin_amdgcn_exp2f(x);
#else
  return exp2f(x);
#endif
}
__device__ __forceinline__ float frcp(float x) {
#if __has_builtin(__builtin_amdgcn_rcpf)
  return __builtin_amdgcn_rcpf(x);
#else
  return 1.0f / x;
#endif
}

// ---------------- Kernel 1: xg = x @ Wih0^T + bih0 + bhh0  -> [B*T, 20] ----
// 64 rows per block staged in LDS via contiguous float4 loads (the 64-row
// slab is one contiguous 14400-float run -> perfectly coalesced).
// Compute: thread = (row r = tid&63, gate-quarter q = tid>>6) -> 5 outputs.
// LDS reads xs[r*225+k]: 225 % 32 == 1 -> bank (r+k)%32 -> conflict-free.
__global__ __launch_bounds__(256)
void xg_gemm(const float* __restrict__ x, const float* __restrict__ Wih,
             const float* __restrict__ bih, const float* __restrict__ bhh,
             float* __restrict__ xg)
{
  __shared__ float xs[64 * D_IN];            // 57600 B
  const int tid = threadIdx.x;
  const size_t base = (size_t)blockIdx.x * 64 * D_IN;
  const float4* src = (const float4*)(x + base);   // base*4 % 16 == 0
  float4* dst = (float4*)xs;
  for (int i = tid; i < (64 * D_IN) / 4; i += 256) dst[i] = src[i];
  __syncthreads();

  const int r = tid & 63;
  const int q = __builtin_amdgcn_readfirstlane(tid >> 6);  // wave-uniform
  float acc[5];
#pragma unroll
  for (int j = 0; j < 5; ++j) acc[j] = bih[5 * q + j] + bhh[5 * q + j];
  const float* xr = xs + r * D_IN;
  const float* wr = Wih + (size_t)(5 * q) * D_IN;
#pragma unroll 3
  for (int k = 0; k < D_IN; ++k) {
    float xv = xr[k];
#pragma unroll
    for (int j = 0; j < 5; ++j)
      acc[j] = fmaf(xv, wr[j * D_IN + k], acc[j]);
  }
  float* op = xg + (size_t)(blockIdx.x * 64 + r) * 20 + 5 * q;
#pragma unroll
  for (int j = 0; j < 5; ++j) op[j] = acc[j];
}

// ---------------- Kernel 2: wave-specialized stage pipeline ----------------
// 6 waves/block, one pipeline stage each: w0=L0, w1=L1, w2=FC1, w3=L2,
// w4=L3, w5=FC2. Wave s processes t = k - s at tick k. Stages exchange
// 5-float h vectors via double-buffered LDS; one barrier per tick.
// Each half-wave (32 lanes) owns one batch element; lanes 0..19 = gates.

__device__ __forceinline__ float activ(float pre, float premul, float postA, float postB) {
  float e = fexp2(pre * premul);
  float s = frcp(1.0f + e);
  return fmaf(postA, s, postB);
}
__device__ __forceinline__ float tanh_(float x) {
  float e2 = fexp2(x * (-2.0f * LOG2E));
  return fmaf(2.0f, frcp(1.0f + e2), -1.0f);
}

#define HB(arr, pp, hh, jj) hb[((((arr) * 2 + (pp)) * 2 + (hh)) << 3) + (jj)]

__global__ __launch_bounds__(384)
void lstm_rec(const float* __restrict__ xg, float* __restrict__ out,
              const float* __restrict__ l1_Whh0,
              const float* __restrict__ l1_Wih1, const float* __restrict__ l1_Whh1,
              const float* __restrict__ l1_bih1, const float* __restrict__ l1_bhh1,
              const float* __restrict__ fc1_W,  const float* __restrict__ fc1_b,
              const float* __restrict__ l2_Wih0, const float* __restrict__ l2_Whh0,
              const float* __restrict__ l2_bih0, const float* __restrict__ l2_bhh0,
              const float* __restrict__ l2_Wih1, const float* __restrict__ l2_Whh1,
              const float* __restrict__ l2_bih1, const float* __restrict__ l2_bhh1,
              const float* __restrict__ fc2_W,  const float* __restrict__ fc2_b)
{
  __shared__ float hb[5 * 2 * 2 * 8];   // [array][buf][elem][slot8]
  const int tid  = threadIdx.x;
  const int wv   = tid >> 6;            // 0..5 stage id
  const int lane = tid & 63;
  const int g    = lane & 31;
  const int half = lane >> 5;
  const int b    = blockIdx.x * 2 + half;
  const size_t rowbase = (size_t)b * T_STEPS;

  for (int i = tid; i < 5 * 2 * 2 * 8; i += 384) hb[i] = 0.f;

  const bool act20 = (g < 20);
  const int  gs = act20 ? g : 0;
  const int  gf = (g < 5) ? g : 0;

  // per-lane activation constants (torch gate order i,f,g,o; lanes 10-14 tanh)
  const bool  is_t   = (g >= 10 && g < 15);
  const float premul = is_t ? (-2.0f * LOG2E) : (-LOG2E);
  const float postA  = is_t ? 2.0f : 1.0f;
  const float postB  = is_t ? -1.0f : 0.0f;

  float wih[5] = {0,0,0,0,0}, whh[5] = {0,0,0,0,0}, bb = 0.f;
  float wf[5]  = {0,0,0,0,0}, fb = 0.f;
  if (wv == 0) {
#pragma unroll
    for (int j = 0; j < 5; ++j) whh[j] = l1_Whh0[gs * 5 + j];
  } else if (wv == 1) {
#pragma unroll
    for (int j = 0; j < 5; ++j) { wih[j] = l1_Wih1[gs * 5 + j]; whh[j] = l1_Whh1[gs * 5 + j]; }
    bb = l1_bih1[gs] + l1_bhh1[gs];
  } else if (wv == 3) {
#pragma unroll
    for (int j = 0; j < 5; ++j) { wih[j] = l2_Wih0[gs * 5 + j]; whh[j] = l2_Whh0[gs * 5 + j]; }
    bb = l2_bih0[gs] + l2_bhh0[gs];
  } else if (wv == 4) {
#pragma unroll
    for (int j = 0; j < 5; ++j) { wih[j] = l2_Wih1[gs * 5 + j]; whh[j] = l2_Whh1[gs * 5 + j]; }
    bb = l2_bih1[gs] + l2_bhh1[gs];
  } else if (wv == 2) {
#pragma unroll
    for (int j = 0; j < 5; ++j) wf[j] = fc1_W[gf * 5 + j];
    fb = fc1_b[gf];
  } else {
#pragma unroll
    for (int j = 0; j < 5; ++j) wf[j] = fc2_W[gf * 5 + j];
    fb = fc2_b[gf];
  }

  float c = 0.f;
  float xq0 = 0.f, xq1 = 0.f, xq2 = 0.f;
  const float* xgp = xg + rowbase * 20 + g;
  if (wv == 0 && act20) { xq0 = xgp[0]; xq1 = xgp[20]; xq2 = xgp[40]; }

  __syncthreads();

  const int NT = T_STEPS + 5;
  for (int k = 0; k < NT; ++k) {
    const int p = k & 1;
    if (wv == 0) {                                  // L0, t = k
      float hp[5];
#pragma unroll
      for (int j = 0; j < 5; ++j) hp[j] = HB(0, p, half, j);
      float pre = xq0;
#pragma unroll
      for (int j = 0; j < 5; ++j) pre = fmaf(whh[j], hp[j], pre);
      float a  = activ(pre, premul, postA, postB);
      float f  = __shfl_down(a, 5, 32);
      float gg = __shfl_down(a, 10, 32);
      float o  = __shfl_down(a, 15, 32);
      float cn = fmaf(f, c, a * gg);
      float hv = o * tanh_(cn);
      if (k < T_STEPS) { c = cn; if (g < 5) HB(0, 1 - p, half, g) = hv; }
      xq0 = xq1; xq1 = xq2;
      int tn = k + 3; if (tn > T_STEPS - 1) tn = T_STEPS - 1;
      xq2 = act20 ? xgp[(size_t)tn * 20] : 0.f;
    } else if (wv == 1) {                           // L1, t = k-1
      int t = k - 1;
      float in[5], hp[5];
#pragma unroll
      for (int j = 0; j < 5; ++j) { in[j] = HB(0, p, half, j); hp[j] = HB(1, p, half, j); }
      float pre = bb;
#pragma unroll
      for (int j = 0; j < 5; ++j) pre = fmaf(wih[j], in[j], pre);
#pragma unroll
      for (int j = 0; j < 5; ++j) pre = fmaf(whh[j], hp[j], pre);
      float a  = activ(pre, premul, postA, postB);
      float f  = __shfl_down(a, 5, 32);
      float gg = __shfl_down(a, 10, 32);
      float o  = __shfl_down(a, 15, 32);
      float cn = fmaf(f, c, a * gg);
      float hv = o * tanh_(cn);
      if (t >= 0 && t < T_STEPS) { c = cn; if (g < 5) HB(1, 1 - p, half, g) = hv; }
    } else if (wv == 2) {                           // FC1+ReLU, t = k-2
      int t = k - 2;
      float in[5];
#pragma unroll
      for (int j = 0; j < 5; ++j) in[j] = HB(1, p, half, j);
      float v = fb;
#pragma unroll
      for (int j = 0; j < 5; ++j) v = fmaf(wf[j], in[j], v);
      v = fmaxf(v, 0.0f);
      if (t >= 0 && t < T_STEPS && g < 5) HB(2, 1 - p, half, g) = v;
    } else if (wv == 3) {                           // L2, t = k-3
      int t = k - 3;
      float in[5], hp[5];
#pragma unroll
      for (int j = 0; j < 5; ++j) { in[j] = HB(2, p, half, j); hp[j] = HB(3, p, half, j); }
      float pre = bb;
#pragma unroll
      for (int j = 0; j < 5; ++j) pre = fmaf(wih[j], in[j], pre);
#pragma unroll
      for (int j = 0; j < 5; ++j) pre = fmaf(whh[j], hp[j], pre);
      float a  = activ(pre, premul, postA, postB);
      float f  = __shfl_down(a, 5, 32);
      float gg = __shfl_down(a, 10, 32);
      float o  = __shfl_down(a, 15, 32);
      float cn = fmaf(f, c, a * gg);
      float hv = o * tanh_(cn);
      if (t >= 0 && t < T_STEPS) { c = cn; if (g < 5) HB(3, 1 - p, half, g) = hv; }
    } else if (wv == 4) {                           // L3, t = k-4
      int t = k - 4;
      float in[5], hp[5];
#pragma unroll
      for (int j = 0; j < 5; ++j) { in[j] = HB(3, p, half, j); hp[j] = HB(4, p, half, j); }
      float pre = bb;
#pragma unroll
      for (int j = 0; j < 5; ++j) pre = fmaf(wih[j], in[j], pre);
#pragma unroll
      for (int j = 0; j < 5; ++j) pre = fmaf(whh[j], hp[j], pre);
      float a  = activ(pre, premul, postA, postB);
      float f  = __shfl_down(a, 5, 32);
      float gg = __shfl_down(a, 10, 32);
      float o  = __shfl_down(a, 15, 32);
      float cn = fmaf(f, c, a * gg);
      float hv = o * tanh_(cn);
      if (t >= 0 && t < T_STEPS) { c = cn; if (g < 5) HB(4, 1 - p, half, g) = hv; }
    } else {                                        // FC2+sigmoid, t = k-5
      int t = k - 5;
      float in[5];
#pragma unroll
      for (int j = 0; j < 5; ++j) in[j] = HB(4, p, half, j);
      float v = fb;
#pragma unroll
      for (int j = 0; j < 5; ++j) v = fmaf(wf[j], in[j], v);
      float sg = frcp(1.0f + fexp2(v * (-LOG2E)));
      if (t >= 0 && t < T_STEPS && g < 5) out[(rowbase + t) * 5 + g] = sg;
    }
    __syncthreads();
  }
}

// ---------------------------------------------------------------------------
extern "C" void kernel_launch(void* const* d_in, const int* in_sizes, int n_in,
                              void* d_out, int out_size, void* d_ws, size_t ws_size,
                              hipStream_t stream)
{
  const float* x        = (const float*)d_in[0];
  const float* l1_Wih0  = (const float*)d_in[1];
  const float* l1_Whh0  = (const float*)d_in[2];
  const float* l1_bih0  = (const float*)d_in[3];
  const float* l1_bhh0  = (const float*)d_in[4];
  const float* l1_Wih1  = (const float*)d_in[5];
  const float* l1_Whh1  = (const float*)d_in[6];
  const float* l1_bih1  = (const float*)d_in[7];
  const float* l1_bhh1  = (const float*)d_in[8];
  const float* fc1_W    = (const float*)d_in[9];
  const float* fc1_b    = (const float*)d_in[10];
  const float* l2_Wih0  = (const float*)d_in[11];
  const float* l2_Whh0  = (const float*)d_in[12];
  const float* l2_bih0  = (const float*)d_in[13];
  const float* l2_bhh0  = (const float*)d_in[14];
  const float* l2_Wih1  = (const float*)d_in[15];
  const float* l2_Whh1  = (const float*)d_in[16];
  const float* l2_bih1  = (const float*)d_in[17];
  const float* l2_bhh1  = (const float*)d_in[18];
  const float* fc2_W    = (const float*)d_in[19];
  const float* fc2_b    = (const float*)d_in[20];

  float* xg  = (float*)d_ws;            // B*T*20*4 = 41,943,040 bytes
  float* out = (float*)d_out;

  xg_gemm<<<dim3((B_SIZE * T_STEPS) / 64), dim3(256), 0, stream>>>(
      x, l1_Wih0, l1_bih0, l1_bhh0, xg);

  lstm_rec<<<dim3(B_SIZE / 2), dim3(384), 0, stream>>>(
      xg, out, l1_Whh0, l1_Wih1, l1_Whh1, l1_bih1, l1_bhh1,
      fc1_W, fc1_b, l2_Wih0, l2_Whh0, l2_bih0, l2_bhh0,
      l2_Wih1, l2_Whh1, l2_bih1, l2_bhh1, fc2_W, fc2_b);
}

// Round 3
// 760.384 us; speedup vs baseline: 1.4787x; 1.0934x over previous
//
#include <hip/hip_runtime.h>
#include <math.h>

#define T_STEPS 1024
#define B_SIZE  512
#define D_IN    225
#define LOG2E   1.4426950408889634f

__device__ __forceinline__ float fexp2(float x) {
#if __has_builtin(__builtin_amdgcn_exp2f)
  return __builtin_amdgcn_exp2f(x);
#else
  return exp2f(x);
#endif
}
__device__ __forceinline__ float frcp(float x) {
#if __has_builtin(__builtin_amdgcn_rcpf)
  return __builtin_amdgcn_rcpf(x);
#else
  return 1.0f / x;
#endif
}

// async global->LDS (16B and 4B variants); LDS dest = uniform base + lane*size
#define GL16(gp, lp) __builtin_amdgcn_global_load_lds(                          \
    (const __attribute__((address_space(1))) void*)(gp),                        \
    (__attribute__((address_space(3))) void*)(lp), 16, 0, 0)
#define GL4(gp, lp)  __builtin_amdgcn_global_load_lds(                          \
    (const __attribute__((address_space(1))) void*)(gp),                        \
    (__attribute__((address_space(3))) void*)(lp), 4, 0, 0)

// -------- Kernel 0: transpose W for layer0 into ws:  Wt[k*32+g], bias at 7200
__global__ __launch_bounds__(256)
void prep_wt(const float* __restrict__ Wih, const float* __restrict__ bih,
             const float* __restrict__ bhh, float* __restrict__ wt)
{
  int i = blockIdx.x * 256 + threadIdx.x;
  if (i < 4500) {
    int k = i / 20, g = i - k * 20;
    wt[k * 32 + g] = Wih[g * D_IN + k];
  } else if (i < 4520) {
    int g = i - 4500;
    wt[7200 + g] = bih[g] + bhh[g];
  }
}

// -------- Kernel 1: xg = x @ Wih0^T + b   [B*T, 20], double-buffered LDS ----
// 256 persistent blocks x 128 threads; 32 tiles of 64 rows each per block.
// Stage via global_load_lds (width 16) -> deep in-flight queue, one
// __syncthreads per tile drains it while compute of current tile runs first.
__global__ __launch_bounds__(128)
void xg_gemm(const float* __restrict__ x, const float* __restrict__ wtg,
             float* __restrict__ xg)
{
  __shared__ __align__(16) float xs[2][64 * D_IN];   // 2 x 57600 B
  __shared__ __align__(16) float wt[7424];           // 29696 B
  const int tid  = threadIdx.x;
  const int lane = tid & 63;
  const int wv   = tid >> 6;            // 0/1

  // stage Wt (7424 dwords = 29 x 256-dword instrs, split across waves)
  if (wv == 0) {
#pragma unroll
    for (int m = 0; m < 15; ++m) GL16(wtg + m * 256 + lane * 4, wt + m * 256);
  } else {
#pragma unroll
    for (int m = 15; m < 29; ++m) GL16(wtg + m * 256 + lane * 4, wt + m * 256);
  }

  const int tile0 = blockIdx.x * 32;
  // stage first x tile (14400 dwords = 56 x 256 + 64)
  {
    const float* src = x + (size_t)tile0 * (64 * D_IN);
    float* dst = xs[0];
    if (wv == 0) {
#pragma unroll
      for (int m = 0; m < 28; ++m) GL16(src + m * 256 + lane * 4, dst + m * 256);
    } else {
#pragma unroll
      for (int m = 28; m < 56; ++m) GL16(src + m * 256 + lane * 4, dst + m * 256);
      GL4(src + 14336 + lane, dst + 14336);
    }
  }
  __syncthreads();

  const int h16 = wv * 16;              // wt row offset for this wave's gates
  const int g10 = wv * 10;              // output gate offset

  for (int t = 0; t < 32; ++t) {
    const int cur = t & 1;
    if (t < 31) {                       // issue next-tile staging (async)
      const float* src = x + (size_t)(tile0 + t + 1) * (64 * D_IN);
      float* dst = xs[cur ^ 1];
      if (wv == 0) {
#pragma unroll
        for (int m = 0; m < 28; ++m) GL16(src + m * 256 + lane * 4, dst + m * 256);
      } else {
#pragma unroll
        for (int m = 28; m < 56; ++m) GL16(src + m * 256 + lane * 4, dst + m * 256);
        GL4(src + 14336 + lane, dst + 14336);
      }
    }
    // compute current tile: row = lane, gates g10..g10+9
    float acc[10];
#pragma unroll
    for (int j = 0; j < 10; ++j) acc[j] = wt[7200 + g10 + j];
    const float* xr = &xs[cur][lane * D_IN];
#pragma unroll 3
    for (int k = 0; k < D_IN; ++k) {
      float xv = xr[k];
      const float* wk = &wt[k * 32 + h16];
#pragma unroll
      for (int j = 0; j < 10; ++j) acc[j] = fmaf(xv, wk[j], acc[j]);
    }
    float* op = xg + (size_t)((tile0 + t) * 64 + lane) * 20 + g10;
#pragma unroll
    for (int j = 0; j < 10; ++j) op[j] = acc[j];

    __syncthreads();                    // drains next-tile loads + compute ds
  }
}

// -------- Kernel 2: wave-specialized stage pipeline, raw barrier ------------
__device__ __forceinline__ float activ(float pre, float premul, float postA, float postB) {
  float e = fexp2(pre * premul);
  float s = frcp(1.0f + e);
  return fmaf(postA, s, postB);
}
__device__ __forceinline__ float tanh_(float x) {
  float e2 = fexp2(x * (-2.0f * LOG2E));
  return fmaf(2.0f, frcp(1.0f + e2), -1.0f);
}

#define HB(arr, pp, hh, jj) hb[((((arr) * 2 + (pp)) * 2 + (hh)) << 3) + (jj)]

// LDS-ordering barrier that does NOT drain vmcnt (global prefetches stay live)
#define BARRIER() asm volatile("s_waitcnt lgkmcnt(0)\n\ts_barrier" ::: "memory")

#define TICKQ(K, Q)                                                            \
  {                                                                            \
    const int k = (K);                                                         \
    const int p = k & 1;                                                       \
    if (wv == 0) {                                  /* L0, t = k */            \
      float hp[5];                                                             \
      for (int j = 0; j < 5; ++j) hp[j] = HB(0, p, half, j);                   \
      float pre = Q;                                                           \
      for (int j = 0; j < 5; ++j) pre = fmaf(whh[j], hp[j], pre);              \
      float a  = activ(pre, premul, postA, postB);                             \
      float f  = __shfl_down(a, 5, 32);                                        \
      float gg = __shfl_down(a, 10, 32);                                       \
      float o  = __shfl_down(a, 15, 32);                                       \
      float cn = fmaf(f, c, a * gg);                                           \
      float hv = o * tanh_(cn);                                                \
      if (k < T_STEPS) { c = cn; if (g < 5) HB(0, 1 - p, half, g) = hv; }      \
      int tn = k + 4; if (tn > T_STEPS - 1) tn = T_STEPS - 1;                  \
      Q = xgp[(size_t)tn * 20];                                                \
    } else if (wv == 1) {                           /* L1, t = k-1 */          \
      int t = k - 1;                                                           \
      float in[5], hp[5];                                                      \
      for (int j = 0; j < 5; ++j) { in[j] = HB(0, p, half, j); hp[j] = HB(1, p, half, j); } \
      float pre = bb;                                                          \
      for (int j = 0; j < 5; ++j) pre = fmaf(wih[j], in[j], pre);              \
      for (int j = 0; j < 5; ++j) pre = fmaf(whh[j], hp[j], pre);              \
      float a  = activ(pre, premul, postA, postB);                             \
      float f  = __shfl_down(a, 5, 32);                                        \
      float gg = __shfl_down(a, 10, 32);                                       \
      float o  = __shfl_down(a, 15, 32);                                       \
      float cn = fmaf(f, c, a * gg);                                           \
      float hv = o * tanh_(cn);                                                \
      if (t >= 0 && t < T_STEPS) { c = cn; if (g < 5) HB(1, 1 - p, half, g) = hv; } \
    } else if (wv == 2) {                           /* FC1+ReLU, t = k-2 */    \
      int t = k - 2;                                                           \
      float in[5];                                                             \
      for (int j = 0; j < 5; ++j) in[j] = HB(1, p, half, j);                   \
      float v = fb;                                                            \
      for (int j = 0; j < 5; ++j) v = fmaf(wf[j], in[j], v);                   \
      v = fmaxf(v, 0.0f);                                                      \
      if (t >= 0 && t < T_STEPS && g < 5) HB(2, 1 - p, half, g) = v;           \
    } else if (wv == 3) {                           /* L2, t = k-3 */          \
      int t = k - 3;                                                           \
      float in[5], hp[5];                                                      \
      for (int j = 0; j < 5; ++j) { in[j] = HB(2, p, half, j); hp[j] = HB(3, p, half, j); } \
      float pre = bb;                                                          \
      for (int j = 0; j < 5; ++j) pre = fmaf(wih[j], in[j], pre);              \
      for (int j = 0; j < 5; ++j) pre = fmaf(whh[j], hp[j], pre);              \
      float a  = activ(pre, premul, postA, postB);                             \
      float f  = __shfl_down(a, 5, 32);                                        \
      float gg = __shfl_down(a, 10, 32);                                       \
      float o  = __shfl_down(a, 15, 32);                                       \
      float cn = fmaf(f, c, a * gg);                                           \
      float hv = o * tanh_(cn);                                                \
      if (t >= 0 && t < T_STEPS) { c = cn; if (g < 5) HB(3, 1 - p, half, g) = hv; } \
    } else if (wv == 4) {                           /* L3, t = k-4 */          \
      int t = k - 4;                                                           \
      float in[5], hp[5];                                                      \
      for (int j = 0; j < 5; ++j) { in[j] = HB(3, p, half, j); hp[j] = HB(4, p, half, j); } \
      float pre = bb;                                                          \
      for (int j = 0; j < 5; ++j) pre = fmaf(wih[j], in[j], pre);              \
      for (int j = 0; j < 5; ++j) pre = fmaf(whh[j], hp[j], pre);              \
      float a  = activ(pre, premul, postA, postB);                             \
      float f  = __shfl_down(a, 5, 32);                                        \
      float gg = __shfl_down(a, 10, 32);                                       \
      float o  = __shfl_down(a, 15, 32);                                       \
      float cn = fmaf(f, c, a * gg);                                           \
      float hv = o * tanh_(cn);                                                \
      if (t >= 0 && t < T_STEPS) { c = cn; if (g < 5) HB(4, 1 - p, half, g) = hv; } \
    } else {                                        /* FC2+sigmoid, t = k-5 */ \
      int t = k - 5;                                                           \
      float in[5];                                                             \
      for (int j = 0; j < 5; ++j) in[j] = HB(4, p, half, j);                   \
      float v = fb;                                                            \
      for (int j = 0; j < 5; ++j) v = fmaf(wf[j], in[j], v);                   \
      float sg = frcp(1.0f + fexp2(v * (-LOG2E)));                             \
      if (t >= 0 && t < T_STEPS && g < 5) out[(rowbase + t) * 5 + g] = sg;     \
    }                                                                          \
    BARRIER();                                                                 \
  }

__global__ __launch_bounds__(384)
void lstm_rec(const float* __restrict__ xg, float* __restrict__ out,
              const float* __restrict__ l1_Whh0,
              const float* __restrict__ l1_Wih1, const float* __restrict__ l1_Whh1,
              const float* __restrict__ l1_bih1, const float* __restrict__ l1_bhh1,
              const float* __restrict__ fc1_W,  const float* __restrict__ fc1_b,
              const float* __restrict__ l2_Wih0, const float* __restrict__ l2_Whh0,
              const float* __restrict__ l2_bih0, const float* __restrict__ l2_bhh0,
              const float* __restrict__ l2_Wih1, const float* __restrict__ l2_Whh1,
              const float* __restrict__ l2_bih1, const float* __restrict__ l2_bhh1,
              const float* __restrict__ fc2_W,  const float* __restrict__ fc2_b)
{
  __shared__ float hb[5 * 2 * 2 * 8];
  const int tid  = threadIdx.x;
  const int wv   = tid >> 6;            // stage id 0..5
  const int lane = tid & 63;
  const int g    = lane & 31;
  const int half = lane >> 5;
  const int b    = blockIdx.x * 2 + half;
  const size_t rowbase = (size_t)b * T_STEPS;

  for (int i = tid; i < 5 * 2 * 2 * 8; i += 384) hb[i] = 0.f;

  const int gs = (g < 20) ? g : 0;
  const int gf = (g < 5) ? g : 0;
  const bool  is_t   = (g >= 10 && g < 15);
  const float premul = is_t ? (-2.0f * LOG2E) : (-LOG2E);
  const float postA  = is_t ? 2.0f : 1.0f;
  const float postB  = is_t ? -1.0f : 0.0f;

  float wih[5] = {0,0,0,0,0}, whh[5] = {0,0,0,0,0}, bb = 0.f;
  float wf[5]  = {0,0,0,0,0}, fb = 0.f;
  if (wv == 0) {
    for (int j = 0; j < 5; ++j) whh[j] = l1_Whh0[gs * 5 + j];
  } else if (wv == 1) {
    for (int j = 0; j < 5; ++j) { wih[j] = l1_Wih1[gs * 5 + j]; whh[j] = l1_Whh1[gs * 5 + j]; }
    bb = l1_bih1[gs] + l1_bhh1[gs];
  } else if (wv == 3) {
    for (int j = 0; j < 5; ++j) { wih[j] = l2_Wih0[gs * 5 + j]; whh[j] = l2_Whh0[gs * 5 + j]; }
    bb = l2_bih0[gs] + l2_bhh0[gs];
  } else if (wv == 4) {
    for (int j = 0; j < 5; ++j) { wih[j] = l2_Wih1[gs * 5 + j]; whh[j] = l2_Whh1[gs * 5 + j]; }
    bb = l2_bih1[gs] + l2_bhh1[gs];
  } else if (wv == 2) {
    for (int j = 0; j < 5; ++j) wf[j] = fc1_W[gf * 5 + j];
    fb = fc1_b[gf];
  } else {
    for (int j = 0; j < 5; ++j) wf[j] = fc2_W[gf * 5 + j];
    fb = fc2_b[gf];
  }

  float c = 0.f;
  const float* xgp = xg + rowbase * 20 + gs;
  float q0 = 0.f, q1 = 0.f, q2 = 0.f, q3 = 0.f;
  if (wv == 0) { q0 = xgp[0]; q1 = xgp[20]; q2 = xgp[40]; q3 = xgp[60]; }

  BARRIER();

  // 258 groups x 4 ticks = 1032 >= 1029 needed; all ticks fully guarded
  for (int grp = 0; grp < 258; ++grp) {
    const int kb = grp * 4;
    TICKQ(kb + 0, q0)
    TICKQ(kb + 1, q1)
    TICKQ(kb + 2, q2)
    TICKQ(kb + 3, q3)
  }
}

// ---------------------------------------------------------------------------
extern "C" void kernel_launch(void* const* d_in, const int* in_sizes, int n_in,
                              void* d_out, int out_size, void* d_ws, size_t ws_size,
                              hipStream_t stream)
{
  const float* x        = (const float*)d_in[0];
  const float* l1_Wih0  = (const float*)d_in[1];
  const float* l1_Whh0  = (const float*)d_in[2];
  const float* l1_bih0  = (const float*)d_in[3];
  const float* l1_bhh0  = (const float*)d_in[4];
  const float* l1_Wih1  = (const float*)d_in[5];
  const float* l1_Whh1  = (const float*)d_in[6];
  const float* l1_bih1  = (const float*)d_in[7];
  const float* l1_bhh1  = (const float*)d_in[8];
  const float* fc1_W    = (const float*)d_in[9];
  const float* fc1_b    = (const float*)d_in[10];
  const float* l2_Wih0  = (const float*)d_in[11];
  const float* l2_Whh0  = (const float*)d_in[12];
  const float* l2_bih0  = (const float*)d_in[13];
  const float* l2_bhh0  = (const float*)d_in[14];
  const float* l2_Wih1  = (const float*)d_in[15];
  const float* l2_Whh1  = (const float*)d_in[16];
  const float* l2_bih1  = (const float*)d_in[17];
  const float* l2_bhh1  = (const float*)d_in[18];
  const float* fc2_W    = (const float*)d_in[19];
  const float* fc2_b    = (const float*)d_in[20];

  float* xg   = (float*)d_ws;                  // 10,485,760 floats
  float* wtws = xg + 10485760;                 // 7,424 floats (transposed W + bias)
  float* out  = (float*)d_out;

  prep_wt<<<dim3(18), dim3(256), 0, stream>>>(l1_Wih0, l1_bih0, l1_bhh0, wtws);

  xg_gemm<<<dim3(256), dim3(128), 0, stream>>>(x, wtws, xg);

  lstm_rec<<<dim3(B_SIZE / 2), dim3(384), 0, stream>>>(
      xg, out, l1_Whh0, l1_Wih1, l1_Whh1, l1_bih1, l1_bhh1,
      fc1_W, fc1_b, l2_Wih0, l2_Whh0, l2_bih0, l2_bhh0,
      l2_Wih1, l2_Whh1, l2_bih1, l2_bhh1, fc2_W, fc2_b);
}

// Round 4
// 548.576 us; speedup vs baseline: 2.0496x; 1.3861x over previous
//
#include <hip/hip_runtime.h>
#include <math.h>

#define T_STEPS 1024
#define B_SIZE  512
#define D_IN    225
#define WT_K    228
#define LOG2E   1.4426950408889634f

__device__ __forceinline__ float fexp2(float x) {
#if __has_builtin(__builtin_amdgcn_exp2f)
  return __builtin_amdgcn_exp2f(x);
#else
  return exp2f(x);
#endif
}
__device__ __forceinline__ float frcp(float x) {
#if __has_builtin(__builtin_amdgcn_rcpf)
  return __builtin_amdgcn_rcpf(x);
#else
  return 1.0f / x;
#endif
}
#define SIG(x) frcp(1.0f + fexp2((x) * (-LOG2E)))
#define TH(x)  fmaf(2.0f, frcp(1.0f + fexp2((x) * (-2.0f * LOG2E))), -1.0f)

#define GL16(gp, lp) __builtin_amdgcn_global_load_lds(                          \
    (const __attribute__((address_space(1))) void*)(gp),                        \
    (__attribute__((address_space(3))) void*)(lp), 16, 0, 0)
#define GL4(gp, lp)  __builtin_amdgcn_global_load_lds(                          \
    (const __attribute__((address_space(1))) void*)(gp),                        \
    (__attribute__((address_space(3))) void*)(lp), 4, 0, 0)

// -------- Kernel 0: wt2[g*228+k] = Wih[g*225+k] (pad 0); bias at 4560 -------
__global__ __launch_bounds__(256)
void prep_wt(const float* __restrict__ Wih, const float* __restrict__ bih,
             const float* __restrict__ bhh, float* __restrict__ wt2)
{
  int i = blockIdx.x * 256 + threadIdx.x;      // 0..4607
  int g = i / WT_K, kk = i - g * WT_K;
  float v = 0.f;
  if (g < 20 && kk < 225) v = Wih[g * 225 + kk];
  if (i >= 4560 && i < 4580) v = bih[i - 4560] + bhh[i - 4560];
  wt2[i] = v;
}

// -------- Kernel 1: xg' (permuted) = x @ Wih0^T + b --------------------------
// 8192 blocks x 256 thr; 64 rows staged in LDS (global_load_lds), W_T + bias
// staged too. Wave w handles gate-type q=w for units 0..4 (gates 5w..5w+4).
// Output layout: xg'[row*20 + 4*u + q]  (unit-major -> one float4 per L0 lane).
__global__ __launch_bounds__(256)
void xg_gemm(const float* __restrict__ x, const float* __restrict__ wtg,
             float* __restrict__ xg)
{
  __shared__ __align__(16) float xs[64 * D_IN];   // 57600 B
  __shared__ __align__(16) float wt[4608];        // 18432 B (total 76032 B -> 2 blocks/CU)
  const int tid  = threadIdx.x;
  const int lane = tid & 63;
  const int w    = __builtin_amdgcn_readfirstlane(tid >> 6);   // 0..3

  {   // stage W_T + bias: 18 x 256-dword chunks (waves 0,1: 5 ea; 2,3: 4 ea)
    int n0 = (w < 2) ? 5 : 4;
    int c0 = (w < 2) ? w * 5 : 10 + (w - 2) * 4;
    for (int m = 0; m < n0; ++m)
      GL16(wtg + (c0 + m) * 256 + lane * 4, wt + (c0 + m) * 256);
  }
  {   // stage x tile: 14400 dwords = 56 x 256 + 64
    const float* src = x + (size_t)blockIdx.x * (64 * D_IN);
    for (int m = 0; m < 14; ++m)
      GL16(src + (w * 14 + m) * 256 + lane * 4, xs + (w * 14 + m) * 256);
    if (w == 0) GL4(src + 14336 + lane, xs + 14336);
  }
  __syncthreads();

  const int row = lane;
  const float* xr = xs + row * D_IN;              // bank (row+k)%32: conflict-free
  const float* wr = wt + (5 * w) * WT_K;          // wave-uniform -> broadcast reads
  float acc[5];
#pragma unroll
  for (int j = 0; j < 5; ++j) acc[j] = wt[4560 + 5 * w + j];

#pragma unroll 8
  for (int kb = 0; kb < 224; kb += 4) {
    float x0 = xr[kb], x1 = xr[kb + 1], x2 = xr[kb + 2], x3 = xr[kb + 3];
#pragma unroll
    for (int j = 0; j < 5; ++j) {
      const float4 wv = *(const float4*)(wr + j * WT_K + kb);
      acc[j] = fmaf(x0, wv.x, acc[j]);
      acc[j] = fmaf(x1, wv.y, acc[j]);
      acc[j] = fmaf(x2, wv.z, acc[j]);
      acc[j] = fmaf(x3, wv.w, acc[j]);
    }
  }
  {
    float xl = xr[224];
#pragma unroll
    for (int j = 0; j < 5; ++j) acc[j] = fmaf(xl, wr[j * WT_K + 224], acc[j]);
  }
  // permuted store: gate (5w+j) -> slot 4*j + w
  float* op = xg + ((size_t)blockIdx.x * 64 + row) * 20 + w;
#pragma unroll
  for (int j = 0; j < 5; ++j) op[4 * j] = acc[j];
}

// -------- Kernel 2: whole 6-stage pipeline inside one half-wave --------------
// Lanes (per 32-lane half): stage = l32/5 (L0,L1,FC1,L2,L3,FC2), u = l32%5;
// lanes 30,31 idle. Each lane computes all 4 gates of its unit (no gate
// shuffles). Cross-stage h exchange: 10 ds_bpermute per tick. No barriers.
__device__ __forceinline__ void tick(int k, float4& Q, float& hv, float& c,
    const float (&wi)[4][5], const float (&wh)[4][5], const float (&bs)[4],
    const float (&wf)[5], float fb, const int (&ii)[5], const int (&ih)[5],
    bool is_l0, bool is_relu, bool is_fc, bool is_fc2, int stage,
    const float*& xqp, float*& outp)
{
  const int hvi = __float_as_int(hv);
  float in[5], hh[5];
#pragma unroll
  for (int j = 0; j < 5; ++j) {
    in[j] = __int_as_float(__builtin_amdgcn_ds_bpermute(ii[j], hvi));
    hh[j] = __int_as_float(__builtin_amdgcn_ds_bpermute(ih[j], hvi));
  }
  const float qv[4] = {Q.x, Q.y, Q.z, Q.w};
  float pre[4];
#pragma unroll
  for (int q = 0; q < 4; ++q) {
    float p = is_l0 ? qv[q] : bs[q];
#pragma unroll
    for (int j = 0; j < 5; ++j) p = fmaf(wi[q][j], in[j], p);
#pragma unroll
    for (int j = 0; j < 5; ++j) p = fmaf(wh[q][j], hh[j], p);
    pre[q] = p;
  }
  float i_ = SIG(pre[0]), f_ = SIG(pre[1]);
  float g_ = TH(pre[2]),  o_ = SIG(pre[3]);
  float cn = fmaf(f_, c, i_ * g_);
  float hl = o_ * TH(cn);
  float fv = fb;
#pragma unroll
  for (int j = 0; j < 5; ++j) fv = fmaf(wf[j], in[j], fv);
  float fs = SIG(fv);
  float fx = is_relu ? fmaxf(fv, 0.0f) : fs;
  float hn = is_fc ? fx : hl;
  bool ok = (k >= stage);
  c  = ok ? cn : c;
  hv = ok ? hn : hv;
  if (k >= 5 && is_fc2) *outp = fs;
  outp += 5;
  if (is_l0) Q = *(const float4*)xqp;
  xqp += 20;
}

__global__ __launch_bounds__(64)
void lstm_fused(const float* __restrict__ xg, float* __restrict__ out,
              const float* __restrict__ l1_Whh0,
              const float* __restrict__ l1_Wih1, const float* __restrict__ l1_Whh1,
              const float* __restrict__ l1_bih1, const float* __restrict__ l1_bhh1,
              const float* __restrict__ fc1_W,  const float* __restrict__ fc1_b,
              const float* __restrict__ l2_Wih0, const float* __restrict__ l2_Whh0,
              const float* __restrict__ l2_bih0, const float* __restrict__ l2_bhh0,
              const float* __restrict__ l2_Wih1, const float* __restrict__ l2_Whh1,
              const float* __restrict__ l2_bih1, const float* __restrict__ l2_bhh1,
              const float* __restrict__ fc2_W,  const float* __restrict__ fc2_b)
{
  const int lane  = threadIdx.x & 63;
  const int half  = lane >> 5;
  const int l32   = lane & 31;
  const int stage = (l32 < 30) ? (l32 / 5) : 6;
  const int u     = (l32 < 30) ? (l32 - stage * 5) : 0;
  const int b     = blockIdx.x * 2 + half;

  const bool is_l0   = (stage == 0);
  const bool is_relu = (stage == 2);
  const bool is_fc   = (stage == 2) || (stage == 5);
  const bool is_fc2  = (stage == 5);

  float wi[4][5] = {}, wh[4][5] = {}, bs[4] = {}, wf[5] = {};
  float fb = 0.f;
  if (stage == 0) {
#pragma unroll
    for (int q = 0; q < 4; ++q)
#pragma unroll
      for (int j = 0; j < 5; ++j) wh[q][j] = l1_Whh0[(u + 5 * q) * 5 + j];
  } else if (stage == 1) {
#pragma unroll
    for (int q = 0; q < 4; ++q) {
#pragma unroll
      for (int j = 0; j < 5; ++j) {
        wi[q][j] = l1_Wih1[(u + 5 * q) * 5 + j];
        wh[q][j] = l1_Whh1[(u + 5 * q) * 5 + j];
      }
      bs[q] = l1_bih1[u + 5 * q] + l1_bhh1[u + 5 * q];
    }
  } else if (stage == 3) {
#pragma unroll
    for (int q = 0; q < 4; ++q) {
#pragma unroll
      for (int j = 0; j < 5; ++j) {
        wi[q][j] = l2_Wih0[(u + 5 * q) * 5 + j];
        wh[q][j] = l2_Whh0[(u + 5 * q) * 5 + j];
      }
      bs[q] = l2_bih0[u + 5 * q] + l2_bhh0[u + 5 * q];
    }
  } else if (stage == 4) {
#pragma unroll
    for (int q = 0; q < 4; ++q) {
#pragma unroll
      for (int j = 0; j < 5; ++j) {
        wi[q][j] = l2_Wih1[(u + 5 * q) * 5 + j];
        wh[q][j] = l2_Whh1[(u + 5 * q) * 5 + j];
      }
      bs[q] = l2_bih1[u + 5 * q] + l2_bhh1[u + 5 * q];
    }
  } else if (stage == 2) {
#pragma unroll
    for (int j = 0; j < 5; ++j) wf[j] = fc1_W[u * 5 + j];
    fb = fc1_b[u];
  } else if (stage == 5) {
#pragma unroll
    for (int j = 0; j < 5; ++j) wf[j] = fc2_W[u * 5 + j];
    fb = fc2_b[u];
  }

  // bpermute byte-indices (loop-invariant). in <- stage-1's lanes, hh <- own.
  int ii[5], ih[5];
  const int bse = half * 32;
  const int inb = (stage >= 1 && stage <= 5) ? (stage - 1) * 5 : 0;
  const int hb_ = (stage <= 5) ? stage * 5 : 0;
#pragma unroll
  for (int j = 0; j < 5; ++j) {
    ii[j] = (bse + inb + j) * 4;
    ih[j] = (bse + hb_ + j) * 4;
  }

  const float* xqp = xg + ((size_t)b * T_STEPS) * 20 + 4 * u;
  float4 qa = *(const float4*)(xqp);
  float4 qb = *(const float4*)(xqp + 20);
  float4 qc = *(const float4*)(xqp + 40);
  xqp += 60;                                   // points at t=3
  float* outp = out + ((size_t)b * T_STEPS) * 5 + u - 25;  // valid from k=5

  float hv = 0.f, c = 0.f;

  // 343 * 3 = 1029 ticks (T + 5 pipeline drain)
  for (int grp = 0; grp < 343; ++grp) {
    const int k = grp * 3;
    tick(k,     qa, hv, c, wi, wh, bs, wf, fb, ii, ih, is_l0, is_relu, is_fc, is_fc2, stage, xqp, outp);
    tick(k + 1, qb, hv, c, wi, wh, bs, wf, fb, ii, ih, is_l0, is_relu, is_fc, is_fc2, stage, xqp, outp);
    tick(k + 2, qc, hv, c, wi, wh, bs, wf, fb, ii, ih, is_l0, is_relu, is_fc, is_fc2, stage, xqp, outp);
  }
}

// ---------------------------------------------------------------------------
extern "C" void kernel_launch(void* const* d_in, const int* in_sizes, int n_in,
                              void* d_out, int out_size, void* d_ws, size_t ws_size,
                              hipStream_t stream)
{
  const float* x        = (const float*)d_in[0];
  const float* l1_Wih0  = (const float*)d_in[1];
  const float* l1_Whh0  = (const float*)d_in[2];
  const float* l1_bih0  = (const float*)d_in[3];
  const float* l1_bhh0  = (const float*)d_in[4];
  const float* l1_Wih1  = (const float*)d_in[5];
  const float* l1_Whh1  = (const float*)d_in[6];
  const float* l1_bih1  = (const float*)d_in[7];
  const float* l1_bhh1  = (const float*)d_in[8];
  const float* fc1_W    = (const float*)d_in[9];
  const float* fc1_b    = (const float*)d_in[10];
  const float* l2_Wih0  = (const float*)d_in[11];
  const float* l2_Whh0  = (const float*)d_in[12];
  const float* l2_bih0  = (const float*)d_in[13];
  const float* l2_bhh0  = (const float*)d_in[14];
  const float* l2_Wih1  = (const float*)d_in[15];
  const float* l2_Whh1  = (const float*)d_in[16];
  const float* l2_bih1  = (const float*)d_in[17];
  const float* l2_bhh1  = (const float*)d_in[18];
  const float* fc2_W    = (const float*)d_in[19];
  const float* fc2_b    = (const float*)d_in[20];

  float* xg   = (float*)d_ws;                  // 10,485,760 floats
  float* wtws = xg + 10485760;                 // 4,608 floats (W_T + bias)
  float* out  = (float*)d_out;

  prep_wt<<<dim3(18), dim3(256), 0, stream>>>(l1_Wih0, l1_bih0, l1_bhh0, wtws);

  xg_gemm<<<dim3((B_SIZE * T_STEPS) / 64), dim3(256), 0, stream>>>(x, wtws, xg);

  lstm_fused<<<dim3(B_SIZE / 2), dim3(64), 0, stream>>>(
      xg, out, l1_Whh0, l1_Wih1, l1_Whh1, l1_bih1, l1_bhh1,
      fc1_W, fc1_b, l2_Wih0, l2_Whh0, l2_bih0, l2_bhh0,
      l2_Wih1, l2_Whh1, l2_bih1, l2_bhh1, fc2_W, fc2_b);
}